// Round 8
// baseline (264.288 us; speedup 1.0000x reference)
//
#include <hip/hip_runtime.h>

typedef __attribute__((ext_vector_type(8))) short short8;
typedef __attribute__((ext_vector_type(8))) _Float16 half8;
typedef __attribute__((ext_vector_type(4))) float f32x4;
typedef __attribute__((ext_vector_type(4))) unsigned short u16x4;

#define NB 8
#define NQL 2048
#define NKL 2048
#define DD 512

static __device__ __forceinline__ unsigned short f2bf(float x){
  unsigned u = __builtin_bit_cast(unsigned, x);
  unsigned r = u + 0x7FFFu + ((u >> 16) & 1u);
  return (unsigned short)(r >> 16);
}
static __device__ __forceinline__ float bf2f(unsigned short h){
  unsigned u = ((unsigned)h) << 16;
  return __builtin_bit_cast(float, u);
}

static __device__ __forceinline__ void stage16(const void* g, void* l){
  __builtin_amdgcn_global_load_lds(
      (const __attribute__((address_space(1))) void*)g,
      (__attribute__((address_space(3))) void*)l, 16, 0, 0);
}

static __device__ __forceinline__ void barrier_lgkm(){
  asm volatile("s_waitcnt lgkmcnt(0)" ::: "memory");
  __builtin_amdgcn_s_barrier();
  asm volatile("" ::: "memory");
}

// ---------------- split fp32 -> bf16 hi/lo, all three W in one launch ----------------
__global__ __launch_bounds__(256) void split3_k(
    const float* __restrict__ Wq, const float* __restrict__ Wk, const float* __restrict__ Wv,
    unsigned short* __restrict__ hiq, unsigned short* __restrict__ loq,
    unsigned short* __restrict__ hik, unsigned short* __restrict__ lok,
    unsigned short* __restrict__ hiv, unsigned short* __restrict__ lov, int n4){
  const int z = blockIdx.y;
  const float* x = (z==0) ? Wq : (z==1) ? Wk : Wv;
  unsigned short* hi = (z==0) ? hiq : (z==1) ? hik : hiv;
  unsigned short* lo = (z==0) ? loq : (z==1) ? lok : lov;
  int i = blockIdx.x*256 + threadIdx.x;
  if (i >= n4) return;
  f32x4 v = reinterpret_cast<const f32x4*>(x)[i];
  u16x4 h, l;
  #pragma unroll
  for (int j=0;j<4;j++){
    unsigned short hh = f2bf(v[j]);
    h[j] = hh;
    l[j] = f2bf(v[j] - bf2f(hh));
  }
  reinterpret_cast<u16x4*>(hi)[i] = h;
  reinterpret_cast<u16x4*>(lo)[i] = l;
}

// ---------------- fused projections: Y = X * W^T (128x128 tile, staged, dbuf) ----------------
// 3-pass split-bf16 MFMA core. Outputs:
// z=0: Q flat [16384][512], fp16 hi + fp16 lo
// z=1: K tiles [b][kt][32][512] fp16 SINGLE, col-group ^ (row&7)
// z=2: V tiles [b][kt][512][32] fp16 SINGLE, k-slot ^ ((dcol>>1)&3)
__global__ __launch_bounds__(256, 2) void proj2_k(
    const float* __restrict__ Xq, const float* __restrict__ Xk, const float* __restrict__ Xv,
    const unsigned short* __restrict__ Wqh, const unsigned short* __restrict__ Wql,
    const unsigned short* __restrict__ Wkh, const unsigned short* __restrict__ Wkl,
    const unsigned short* __restrict__ Wvh, const unsigned short* __restrict__ Wvl,
    _Float16* __restrict__ Yqh, _Float16* __restrict__ Yql,
    _Float16* __restrict__ Ykt,
    _Float16* __restrict__ Yvt)
{
  __shared__ unsigned short AB[2][4][128][32];   // 64 KB

  const int z = blockIdx.z;
  const float* X          = (z==0) ? Xq  : (z==1) ? Xk  : Xv;
  const unsigned short* Wh = (z==0) ? Wqh : (z==1) ? Wkh : Wvh;
  const unsigned short* Wl = (z==0) ? Wql : (z==1) ? Wkl : Wvl;

  const int mbase = blockIdx.x * 128;
  const int nbase = blockIdx.y * 128;
  const int tid = threadIdx.x;
  const int w = tid >> 6, lane = tid & 63;
  const int l15 = lane & 15, l4 = lane >> 4;
  const int wr = w >> 1, wc = w & 1;

  const int arow = tid >> 1, ahalf = tid & 1;
  const int brow_l = w*16 + (lane>>2);
  const int bkg    = (lane & 3) ^ ((lane >> 3) & 3);

  f32x4 acc[4][4];
  #pragma unroll
  for (int m=0;m<4;m++)
    #pragma unroll
    for (int n=0;n<4;n++) acc[m][n] = (f32x4){0.f,0.f,0.f,0.f};

  f32x4 xa[4];
  {
    const f32x4* xp = reinterpret_cast<const f32x4*>(X + (size_t)(mbase+arow)*DD + ahalf*16);
    #pragma unroll
    for (int q=0;q<4;q++) xa[q] = xp[q];
  }
  {
    unsigned short* lB = &AB[0][2][0][0] + w*512;
    #pragma unroll
    for (int r=0;r<2;r++){
      const size_t gh = (size_t)(nbase + r*64 + brow_l)*DD + bkg*8;
      stage16(Wh + gh, lB + r*2048);
      stage16(Wl + gh, lB + 4096 + r*2048);
    }
  }
  {
    asm volatile("s_waitcnt vmcnt(4)" ::: "memory");
    short8 h0,h1,l0,l1;
    #pragma unroll
    for (int q=0;q<2;q++){
      #pragma unroll
      for (int j=0;j<4;j++){
        float v0 = xa[q*2][j], v1 = xa[q*2+1][j];
        unsigned short a = f2bf(v0); unsigned short b = f2bf(v1);
        if (q==0){ h0[j]=(short)a; h0[4+j]=(short)b; l0[j]=(short)f2bf(v0-bf2f(a)); l0[4+j]=(short)f2bf(v1-bf2f(b)); }
        else     { h1[j]=(short)a; h1[4+j]=(short)b; l1[j]=(short)f2bf(v0-bf2f(a)); l1[4+j]=(short)f2bf(v1-bf2f(b)); }
      }
    }
    const int sw = (arow>>1)&3;
    const int cg0 = (ahalf*2) ^ sw, cg1 = (ahalf*2+1) ^ sw;
    *reinterpret_cast<short8*>(&AB[0][0][arow][cg0*8]) = h0;
    *reinterpret_cast<short8*>(&AB[0][0][arow][cg1*8]) = h1;
    *reinterpret_cast<short8*>(&AB[0][1][arow][cg0*8]) = l0;
    *reinterpret_cast<short8*>(&AB[0][1][arow][cg1*8]) = l1;
  }

  const int asw = (l15>>1)&3;

  #pragma unroll 1
  for (int s=0; s<16; ++s){
    const int cur = s&1, nxt = cur^1;
    asm volatile("s_waitcnt vmcnt(0)" ::: "memory");
    barrier_lgkm();

    if (s < 15){
      const f32x4* xp = reinterpret_cast<const f32x4*>(X + (size_t)(mbase+arow)*DD + (s+1)*32 + ahalf*16);
      #pragma unroll
      for (int q=0;q<4;q++) xa[q] = xp[q];
      unsigned short* lB = &AB[nxt][2][0][0] + w*512;
      #pragma unroll
      for (int r=0;r<2;r++){
        const size_t gh = (size_t)(nbase + r*64 + brow_l)*DD + (s+1)*32 + bkg*8;
        stage16(Wh + gh, lB + r*2048);
        stage16(Wl + gh, lB + 4096 + r*2048);
      }
    }

    short8 ah[4], al[4], bh[4], bl[4];
    #pragma unroll
    for (int m=0;m<4;m++){
      const int rA = wr*64 + m*16 + l15;
      const int cg = (l4 ^ asw)*8;
      ah[m] = *reinterpret_cast<const short8*>(&AB[cur][0][rA][cg]);
      al[m] = *reinterpret_cast<const short8*>(&AB[cur][1][rA][cg]);
    }
    #pragma unroll
    for (int n=0;n<4;n++){
      const int rB = wc*64 + n*16 + l15;
      const int cg = (l4 ^ asw)*8;
      bh[n] = *reinterpret_cast<const short8*>(&AB[cur][2][rB][cg]);
      bl[n] = *reinterpret_cast<const short8*>(&AB[cur][3][rB][cg]);
    }
    #pragma unroll
    for (int m=0;m<4;m++)
      #pragma unroll
      for (int n=0;n<4;n++) acc[m][n] = __builtin_amdgcn_mfma_f32_16x16x32_bf16(ah[m], bh[n], acc[m][n], 0,0,0);
    #pragma unroll
    for (int m=0;m<4;m++)
      #pragma unroll
      for (int n=0;n<4;n++) acc[m][n] = __builtin_amdgcn_mfma_f32_16x16x32_bf16(ah[m], bl[n], acc[m][n], 0,0,0);
    #pragma unroll
    for (int m=0;m<4;m++)
      #pragma unroll
      for (int n=0;n<4;n++) acc[m][n] = __builtin_amdgcn_mfma_f32_16x16x32_bf16(al[m], bh[n], acc[m][n], 0,0,0);

    if (s < 15){
      asm volatile("s_waitcnt vmcnt(4)" ::: "memory");
      short8 h0,h1,l0,l1;
      #pragma unroll
      for (int q=0;q<2;q++){
        #pragma unroll
        for (int j=0;j<4;j++){
          float v0 = xa[q*2][j], v1 = xa[q*2+1][j];
          unsigned short a = f2bf(v0); unsigned short b = f2bf(v1);
          if (q==0){ h0[j]=(short)a; h0[4+j]=(short)b; l0[j]=(short)f2bf(v0-bf2f(a)); l0[4+j]=(short)f2bf(v1-bf2f(b)); }
          else     { h1[j]=(short)a; h1[4+j]=(short)b; l1[j]=(short)f2bf(v0-bf2f(a)); l1[4+j]=(short)f2bf(v1-bf2f(b)); }
        }
      }
      const int sw = (arow>>1)&3;
      const int cg0 = (ahalf*2) ^ sw, cg1 = (ahalf*2+1) ^ sw;
      *reinterpret_cast<short8*>(&AB[nxt][0][arow][cg0*8]) = h0;
      *reinterpret_cast<short8*>(&AB[nxt][0][arow][cg1*8]) = h1;
      *reinterpret_cast<short8*>(&AB[nxt][1][arow][cg0*8]) = l0;
      *reinterpret_cast<short8*>(&AB[nxt][1][arow][cg1*8]) = l1;
    }
  }

  #pragma unroll
  for (int m=0;m<4;m++){
    #pragma unroll
    for (int n=0;n<4;n++){
      #pragma unroll
      for (int j=0;j<4;j++){
        const int row = mbase + wr*64 + m*16 + l4*4 + j;
        const int col = nbase + wc*64 + n*16 + l15;
        const float y = acc[m][n][j];
        if (z == 0){
          const _Float16 h = (_Float16)y;
          const _Float16 l = (_Float16)(y - (float)h);
          const size_t idx = (size_t)row*DD + col;
          Yqh[idx] = h; Yql[idx] = l;
        } else if (z == 1){
          const int bb = row >> 11, nn = row & 2047, kt = nn >> 5;
          const size_t tb = ((size_t)(bb*64 + kt)) << 14;
          const int kr = nn & 31, cg = col >> 3, ci = col & 7;
          const size_t idx = tb + ((size_t)kr)*512 + (size_t)((((cg ^ (kr & 7)) << 3)) | ci);
          Ykt[idx] = (_Float16)y;
        } else {
          const int bb = row >> 11, nn = row & 2047, kt = nn >> 5;
          const size_t tb = ((size_t)(bb*64 + kt)) << 14;
          const int kk = nn & 31;
          const size_t idx = tb + ((size_t)col)*32 + (size_t)(((((kk >> 3) ^ ((col >> 1) & 3)) << 3)) | (kk & 7));
          Yvt[idx] = (_Float16)y;
        }
      }
    }
  }
}

// ---------------- fused flash attention: 2-barrier pipelined (PV lags QK^T by 1 step) ----------------
// Per step t: barA -> stage K(t+1) -> [rescale(t-1); PV(t-1) || QK^T(t)] -> partials
//             -> barB -> stage V(t+1) -> combine -> P(t)/sc(t)/m/l.
// K,V,P,sc,m all parity double-buffered. Epilogue peels PV(63).
__global__ __launch_bounds__(512, 2) void attn_k(
    const _Float16* __restrict__ Qh, const _Float16* __restrict__ Ql,
    const _Float16* __restrict__ Kt,
    const _Float16* __restrict__ Vt,
    float* __restrict__ Out)
{
  __shared__ _Float16 K_lds[2][32][512];   // 64 KB dbuf
  __shared__ _Float16 V_lds[2][512][32];   // 64 KB dbuf
  __shared__ _Float16 P_s[2][64][40];      // 10 KB dbuf
  __shared__ float pm_s[64][2], ps_s[64][2];
  __shared__ float m_s[2][64], l_s[64], sc_s[2][64];

  const int bid = blockIdx.x;
  const int b  = bid & 7;
  const int qt = bid >> 3;
  const int tid = threadIdx.x;
  const int w = tid >> 6, lane = tid & 63;
  const int l15 = lane & 15, l4 = lane >> 4;
  const int rw = w & 3,  cw = w >> 2;   // S^T frag: q-rows rw*16.., k-cols cw*16..
  const int orw = w >> 2, ocw = w & 3;  // O: rows orw*32.., cols ocw*128..

  half8 qhf[16], qlf[16];
  {
    const size_t qoff = (size_t)(b*NQL + qt*64 + rw*16 + l15)*DD + l4*8;
    #pragma unroll
    for (int kc=0;kc<16;kc++){
      qhf[kc] = *reinterpret_cast<const half8*>(Qh + qoff + kc*32);
      qlf[kc] = *reinterpret_cast<const half8*>(Ql + qoff + kc*32);
    }
  }

  f32x4 o[2][8];
  #pragma unroll
  for (int i=0;i<2;i++)
    #pragma unroll
    for (int j=0;j<8;j++) o[i][j] = (f32x4){0.f,0.f,0.f,0.f};

  if (tid < 64){ m_s[0][tid] = -1e30f; l_s[tid] = 0.f; }

  const _Float16* gK = Kt + ((size_t)(b*64) << 14);
  const _Float16* gV = Vt + ((size_t)(b*64) << 14);
  const int goff  = w*512 + lane*8;   // fp16 elems
  const int lbase = w*512;            // wave-uniform dest base

  // prologue: stage K(0)->K[0], V(0)->V[0]
  {
    _Float16* lK = &K_lds[0][0][0];
    _Float16* lV = &V_lds[0][0][0];
    #pragma unroll
    for (int r=0;r<4;r++) stage16(gK + r*4096 + goff, lK + r*4096 + lbase);
    #pragma unroll
    for (int r=0;r<4;r++) stage16(gV + r*4096 + goff, lV + r*4096 + lbase);
  }

  const int krow = cw*16 + l15;
  const int kx = krow & 7;
  const int row_i = rw*16 + l15;     // this lane's q-row (local)
  const int prow0 = orw*32 + l15, prow1 = orw*32 + 16 + l15;

  #pragma unroll 1
  for (int kt=0; kt<64; ++kt){
    const int par = kt & 1;
    asm volatile("s_waitcnt vmcnt(0)" ::: "memory");   // K(t),V(t) resident
    barrier_lgkm();                                    // bar A — staged data + P(t-1)/sc(t-1) visible

    // stage K(t+1) -> K[par^1] (full-step lead)
    if (kt < 63){
      const _Float16* g = gK + ((size_t)(kt+1) << 14);
      _Float16* lK = &K_lds[par^1][0][0];
      #pragma unroll
      for (int r=0;r<4;r++) stage16(g + r*4096 + goff, lK + r*4096 + lbase);
    }

    // ---- merged MFMA superphase: rescale(t-1) + PV(t-1) interleaved with QK^T(t) ----
    f32x4 shh = (f32x4){0.f,0.f,0.f,0.f};
    f32x4 shl = (f32x4){0.f,0.f,0.f,0.f};
    half8 pa0, pa1;
    const bool dopv = (kt > 0);
    if (dopv){
      float scs[2][4];
      bool need = false;
      #pragma unroll
      for (int pr=0; pr<2; pr++)
        #pragma unroll
        for (int j=0;j<4;j++){
          const float s0 = sc_s[par^1][orw*32 + pr*16 + l4*4 + j];
          scs[pr][j] = s0;
          need = need || (s0 < 0.999999f);
        }
      if (__any(need)){
        #pragma unroll
        for (int pr=0;pr<2;pr++)
          #pragma unroll
          for (int c=0;c<8;c++)
            #pragma unroll
            for (int j=0;j<4;j++) o[pr][c][j] *= scs[pr][j];
      }
      pa0 = *reinterpret_cast<const half8*>(&P_s[par^1][prow0][l4*8]);
      pa1 = *reinterpret_cast<const half8*>(&P_s[par^1][prow1][l4*8]);
    }
    __builtin_amdgcn_s_setprio(1);
    #pragma unroll
    for (int u=0; u<16; ++u){
      const int cg = ((u*4 + l4) ^ kx) << 3;
      const half8 kf = *reinterpret_cast<const half8*>(&K_lds[par][krow][cg]);
      shh = __builtin_amdgcn_mfma_f32_16x16x32_f16(kf, qhf[u], shh, 0,0,0);
      shl = __builtin_amdgcn_mfma_f32_16x16x32_f16(kf, qlf[u], shl, 0,0,0);
      if (dopv && u < 8){
        const int dcol = ocw*128 + u*16 + l15;
        const int vb = (l4 ^ ((dcol>>1)&3)) << 3;
        const half8 vv = *reinterpret_cast<const half8*>(&V_lds[par^1][dcol][vb]);
        o[0][u] = __builtin_amdgcn_mfma_f32_16x16x32_f16(pa0, vv, o[0][u], 0,0,0);
        o[1][u] = __builtin_amdgcn_mfma_f32_16x16x32_f16(pa1, vv, o[1][u], 0,0,0);
      }
    }
    __builtin_amdgcn_s_setprio(0);
    const f32x4 sv = shh + shl;   // sv[r] = S[row_i][cw*16 + l4*4 + r]

    // ---- per-wave softmax partials ----
    float mw = fmaxf(fmaxf(sv[0],sv[1]), fmaxf(sv[2],sv[3]));
    mw = fmaxf(mw, __shfl_xor(mw, 16));
    mw = fmaxf(mw, __shfl_xor(mw, 32));
    float p0 = __expf(sv[0]-mw), p1 = __expf(sv[1]-mw);
    float p2 = __expf(sv[2]-mw), p3 = __expf(sv[3]-mw);
    float ssum = p0+p1+p2+p3;
    ssum += __shfl_xor(ssum, 16);
    ssum += __shfl_xor(ssum, 32);
    if (l4 == 0){ pm_s[row_i][cw] = mw; ps_s[row_i][cw] = ssum; }
    barrier_lgkm();                                    // bar B — partials ready; V(t-1)/P(t-1) reads drained

    // stage V(t+1) -> V[par^1] (≈1-step lead; buffer freed by barB)
    if (kt < 63){
      const _Float16* g = gV + ((size_t)(kt+1) << 14);
      _Float16* lV = &V_lds[par^1][0][0];
      #pragma unroll
      for (int r=0;r<4;r++) stage16(g + r*4096 + goff, lV + r*4096 + lbase);
    }

    // ---- combine partials; write P(t), sc(t), m, l ----
    {
      const float m0 = pm_s[row_i][0], m1 = pm_s[row_i][1];
      const float m_old = m_s[par][row_i];
      const float m_new = fmaxf(fmaxf(m0, m1), m_old);
      const float c = __expf(mw - m_new);
      p0 *= c; p1 *= c; p2 *= c; p3 *= c;
      if (cw == 0 && l4 == 0){
        const float e_old = __expf(m_old - m_new);
        const float e1    = __expf(m1 - m_new);
        l_s[row_i] = l_s[row_i]*e_old + ps_s[row_i][0]*c + ps_s[row_i][1]*e1;
        m_s[par^1][row_i] = m_new;
        sc_s[par][row_i] = e_old;
      }
      const unsigned short h0 = __builtin_bit_cast(unsigned short, (_Float16)p0);
      const unsigned short h1 = __builtin_bit_cast(unsigned short, (_Float16)p1);
      const unsigned short h2 = __builtin_bit_cast(unsigned short, (_Float16)p2);
      const unsigned short h3 = __builtin_bit_cast(unsigned short, (_Float16)p3);
      uint2 hv;
      hv.x = (unsigned)h0 | ((unsigned)h1<<16);
      hv.y = (unsigned)h2 | ((unsigned)h3<<16);
      *reinterpret_cast<uint2*>(&P_s[par][row_i][cw*16 + l4*4]) = hv;
    }
  }

  barrier_lgkm();   // publish P(63)/sc(63)/l_s

  // ---- epilogue: rescale(63) + PV(63) + normalize + store ----
  {
    float scs[2][4];
    bool need = false;
    #pragma unroll
    for (int pr=0; pr<2; pr++)
      #pragma unroll
      for (int j=0;j<4;j++){
        const float s0 = sc_s[1][orw*32 + pr*16 + l4*4 + j];
        scs[pr][j] = s0;
        need = need || (s0 < 0.999999f);
      }
    if (__any(need)){
      #pragma unroll
      for (int pr=0;pr<2;pr++)
        #pragma unroll
        for (int c=0;c<8;c++)
          #pragma unroll
          for (int j=0;j<4;j++) o[pr][c][j] *= scs[pr][j];
    }
    const half8 pa0 = *reinterpret_cast<const half8*>(&P_s[1][prow0][l4*8]);
    const half8 pa1 = *reinterpret_cast<const half8*>(&P_s[1][prow1][l4*8]);
    #pragma unroll
    for (int cc=0; cc<8; ++cc){
      const int dcol = ocw*128 + cc*16 + l15;
      const int vb = (l4 ^ ((dcol>>1)&3)) << 3;
      const half8 vv = *reinterpret_cast<const half8*>(&V_lds[1][dcol][vb]);
      o[0][cc] = __builtin_amdgcn_mfma_f32_16x16x32_f16(pa0, vv, o[0][cc], 0,0,0);
      o[1][cc] = __builtin_amdgcn_mfma_f32_16x16x32_f16(pa1, vv, o[1][cc], 0,0,0);
    }
  }

  #pragma unroll
  for (int pr=0;pr<2;pr++){
    #pragma unroll
    for (int j=0;j<4;j++){
      const int row = orw*32 + pr*16 + l4*4 + j;
      const float inv = 1.0f / l_s[row];
      const size_t obase = (size_t)(b*NQL + qt*64 + row)*DD;
      #pragma unroll
      for (int c=0;c<8;c++){
        const int col = ocw*128 + c*16 + l15;
        Out[obase + col] = o[pr][c][j]*inv;
      }
    }
  }
}

extern "C" void kernel_launch(void* const* d_in, const int* in_sizes, int n_in,
                              void* d_out, int out_size, void* d_ws, size_t ws_size,
                              hipStream_t stream) {
  const float* query = (const float*)d_in[0];
  const float* key   = (const float*)d_in[1];
  const float* value = (const float*)d_in[2];
  const float* Wq    = (const float*)d_in[3];
  const float* Wk    = (const float*)d_in[4];
  const float* Wv    = (const float*)d_in[5];
  float* out = (float*)d_out;

  const size_t SB = (size_t)NB*NQL*DD;   // 8,388,608 elems
  const size_t WB = (size_t)DD*DD;

  unsigned short* p = (unsigned short*)d_ws;
  unsigned short *wqh = p,        *wql = p +   WB;
  unsigned short *wkh = p + 2*WB, *wkl = p + 3*WB;
  unsigned short *wvh = p + 4*WB, *wvl = p + 5*WB;
  _Float16* q0 = (_Float16*)(p + 6*WB);
  _Float16 *qh16 = q0,          *ql16 = q0 + SB;
  _Float16 *Kt16 = q0 + 2*SB;                 // [8][64][32][512] fp16
  _Float16 *Vt16 = q0 + 3*SB;                 // [8][64][512][32] fp16

  dim3 sg(256, 3);
  split3_k<<<sg, 256, 0, stream>>>(Wq, Wk, Wv, wqh, wql, wkh, wkl, wvh, wvl, (int)(WB/4));

  dim3 pg(128, 4, 3);
  proj2_k<<<pg, 256, 0, stream>>>(query, key, value,
                                  wqh, wql, wkh, wkl, wvh, wvl,
                                  qh16, ql16, Kt16, Vt16);

  attn_k<<<256, 512, 0, stream>>>(qh16, ql16, Kt16, Vt16, out);
}

// Round 9
// 235.590 us; speedup vs baseline: 1.1218x; 1.1218x over previous
//
#include <hip/hip_runtime.h>

typedef __attribute__((ext_vector_type(8))) short short8;
typedef __attribute__((ext_vector_type(8))) _Float16 half8;
typedef __attribute__((ext_vector_type(4))) float f32x4;
typedef __attribute__((ext_vector_type(4))) unsigned short u16x4;
typedef __attribute__((ext_vector_type(4))) _Float16 half4;

#define NB 8
#define NQL 2048
#define NKL 2048
#define DD 512

static __device__ __forceinline__ void stage16(const void* g, void* l){
  __builtin_amdgcn_global_load_lds(
      (const __attribute__((address_space(1))) void*)g,
      (__attribute__((address_space(3))) void*)l, 16, 0, 0);
}

static __device__ __forceinline__ void barrier_lgkm(){
  asm volatile("s_waitcnt lgkmcnt(0)" ::: "memory");
  __builtin_amdgcn_s_barrier();
  asm volatile("" ::: "memory");
}

// ---------------- convert fp32 W -> fp16 single, all three in one launch ----------------
__global__ __launch_bounds__(256) void split3_k(
    const float* __restrict__ Wq, const float* __restrict__ Wk, const float* __restrict__ Wv,
    _Float16* __restrict__ w16q, _Float16* __restrict__ w16k, _Float16* __restrict__ w16v,
    int n4){
  const int z = blockIdx.y;
  const float* x = (z==0) ? Wq : (z==1) ? Wk : Wv;
  _Float16* o16 = (z==0) ? w16q : (z==1) ? w16k : w16v;
  int i = blockIdx.x*256 + threadIdx.x;
  if (i >= n4) return;
  f32x4 v = reinterpret_cast<const f32x4*>(x)[i];
  half4 h;
  #pragma unroll
  for (int j=0;j<4;j++) h[j] = (_Float16)v[j];
  reinterpret_cast<half4*>(o16)[i] = h;
}

// ---------------- fused projections: Y = X * W^T (128x128 tile, 2-pass fp16, dbuf) ----------------
// A = X split fp16 hi/lo (in-register convert), B = W fp16 single (gload_lds staged).
// z=0: Q flat [16384][512], fp16 hi + fp16 lo
// z=1: K tiles [b][kt][32][512] fp16 SINGLE, col-group ^ (row&7)
// z=2: V tiles [b][kt][512][32] fp16 SINGLE, k-slot ^ ((dcol>>1)&3)
__global__ __launch_bounds__(256, 2) void proj2_k(
    const float* __restrict__ Xq, const float* __restrict__ Xk, const float* __restrict__ Xv,
    const _Float16* __restrict__ W16q, const _Float16* __restrict__ W16k, const _Float16* __restrict__ W16v,
    _Float16* __restrict__ Yqh, _Float16* __restrict__ Yql,
    _Float16* __restrict__ Ykt,
    _Float16* __restrict__ Yvt)
{
  __shared__ _Float16 AB[2][3][128][32];   // 48 KB: planes 0=Ah 1=Al 2=W

  const int z = blockIdx.z;
  const float*    X  = (z==0) ? Xq   : (z==1) ? Xk   : Xv;
  const _Float16* Wf = (z==0) ? W16q : (z==1) ? W16k : W16v;

  const int mbase = blockIdx.x * 128;
  const int nbase = blockIdx.y * 128;
  const int tid = threadIdx.x;
  const int w = tid >> 6, lane = tid & 63;
  const int l15 = lane & 15, l4 = lane >> 4;
  const int wr = w >> 1, wc = w & 1;

  const int arow = tid >> 1, ahalf = tid & 1;
  const int brow_l = w*16 + (lane>>2);
  const int bkg    = (lane & 3) ^ ((lane >> 3) & 3);

  f32x4 acc[4][4];
  #pragma unroll
  for (int m=0;m<4;m++)
    #pragma unroll
    for (int n=0;n<4;n++) acc[m][n] = (f32x4){0.f,0.f,0.f,0.f};

  f32x4 xa[4];
  {
    const f32x4* xp = reinterpret_cast<const f32x4*>(X + (size_t)(mbase+arow)*DD + ahalf*16);
    #pragma unroll
    for (int q=0;q<4;q++) xa[q] = xp[q];
  }
  {
    _Float16* lB = &AB[0][2][0][0] + w*512;
    #pragma unroll
    for (int r=0;r<2;r++){
      const size_t gh = (size_t)(nbase + r*64 + brow_l)*DD + bkg*8;
      stage16(Wf + gh, lB + r*2048);
    }
  }
  {
    asm volatile("s_waitcnt vmcnt(2)" ::: "memory");   // A loads done, W stages outstanding
    half8 h0,h1,l0,l1;
    #pragma unroll
    for (int j=0;j<4;j++){
      float v0 = xa[0][j], v1 = xa[1][j];
      h0[j] = (_Float16)v0; h0[4+j] = (_Float16)v1;
      l0[j] = (_Float16)(v0 - (float)h0[j]); l0[4+j] = (_Float16)(v1 - (float)h0[4+j]);
      float v2 = xa[2][j], v3 = xa[3][j];
      h1[j] = (_Float16)v2; h1[4+j] = (_Float16)v3;
      l1[j] = (_Float16)(v2 - (float)h1[j]); l1[4+j] = (_Float16)(v3 - (float)h1[4+j]);
    }
    const int sw = (arow>>1)&3;
    const int cg0 = (ahalf*2) ^ sw, cg1 = (ahalf*2+1) ^ sw;
    *reinterpret_cast<half8*>(&AB[0][0][arow][cg0*8]) = h0;
    *reinterpret_cast<half8*>(&AB[0][0][arow][cg1*8]) = h1;
    *reinterpret_cast<half8*>(&AB[0][1][arow][cg0*8]) = l0;
    *reinterpret_cast<half8*>(&AB[0][1][arow][cg1*8]) = l1;
  }

  const int asw = (l15>>1)&3;

  #pragma unroll 1
  for (int s=0; s<16; ++s){
    const int cur = s&1, nxt = cur^1;
    asm volatile("s_waitcnt vmcnt(0)" ::: "memory");
    barrier_lgkm();

    if (s < 15){
      const f32x4* xp = reinterpret_cast<const f32x4*>(X + (size_t)(mbase+arow)*DD + (s+1)*32 + ahalf*16);
      #pragma unroll
      for (int q=0;q<4;q++) xa[q] = xp[q];
      _Float16* lB = &AB[nxt][2][0][0] + w*512;
      #pragma unroll
      for (int r=0;r<2;r++){
        const size_t gh = (size_t)(nbase + r*64 + brow_l)*DD + (s+1)*32 + bkg*8;
        stage16(Wf + gh, lB + r*2048);
      }
    }

    half8 ah[4], al[4], wf[4];
    #pragma unroll
    for (int m=0;m<4;m++){
      const int rA = wr*64 + m*16 + l15;
      const int cg = (l4 ^ asw)*8;
      ah[m] = *reinterpret_cast<const half8*>(&AB[cur][0][rA][cg]);
      al[m] = *reinterpret_cast<const half8*>(&AB[cur][1][rA][cg]);
    }
    #pragma unroll
    for (int n=0;n<4;n++){
      const int rB = wc*64 + n*16 + l15;
      const int cg = (l4 ^ asw)*8;
      wf[n] = *reinterpret_cast<const half8*>(&AB[cur][2][rB][cg]);
    }
    #pragma unroll
    for (int m=0;m<4;m++)
      #pragma unroll
      for (int n=0;n<4;n++) acc[m][n] = __builtin_amdgcn_mfma_f32_16x16x32_f16(ah[m], wf[n], acc[m][n], 0,0,0);
    #pragma unroll
    for (int m=0;m<4;m++)
      #pragma unroll
      for (int n=0;n<4;n++) acc[m][n] = __builtin_amdgcn_mfma_f32_16x16x32_f16(al[m], wf[n], acc[m][n], 0,0,0);

    if (s < 15){
      asm volatile("s_waitcnt vmcnt(2)" ::: "memory");  // A loads done, W stages outstanding
      half8 h0,h1,l0,l1;
      #pragma unroll
      for (int j=0;j<4;j++){
        float v0 = xa[0][j], v1 = xa[1][j];
        h0[j] = (_Float16)v0; h0[4+j] = (_Float16)v1;
        l0[j] = (_Float16)(v0 - (float)h0[j]); l0[4+j] = (_Float16)(v1 - (float)h0[4+j]);
        float v2 = xa[2][j], v3 = xa[3][j];
        h1[j] = (_Float16)v2; h1[4+j] = (_Float16)v3;
        l1[j] = (_Float16)(v2 - (float)h1[j]); l1[4+j] = (_Float16)(v3 - (float)h1[4+j]);
      }
      const int sw = (arow>>1)&3;
      const int cg0 = (ahalf*2) ^ sw, cg1 = (ahalf*2+1) ^ sw;
      *reinterpret_cast<half8*>(&AB[nxt][0][arow][cg0*8]) = h0;
      *reinterpret_cast<half8*>(&AB[nxt][0][arow][cg1*8]) = h1;
      *reinterpret_cast<half8*>(&AB[nxt][1][arow][cg0*8]) = l0;
      *reinterpret_cast<half8*>(&AB[nxt][1][arow][cg1*8]) = l1;
    }
  }

  #pragma unroll
  for (int m=0;m<4;m++){
    #pragma unroll
    for (int n=0;n<4;n++){
      #pragma unroll
      for (int j=0;j<4;j++){
        const int row = mbase + wr*64 + m*16 + l4*4 + j;
        const int col = nbase + wc*64 + n*16 + l15;
        const float y = acc[m][n][j];
        if (z == 0){
          const _Float16 h = (_Float16)y;
          const _Float16 l = (_Float16)(y - (float)h);
          const size_t idx = (size_t)row*DD + col;
          Yqh[idx] = h; Yql[idx] = l;
        } else if (z == 1){
          const int bb = row >> 11, nn = row & 2047, kt = nn >> 5;
          const size_t tb = ((size_t)(bb*64 + kt)) << 14;
          const int kr = nn & 31, cg = col >> 3, ci = col & 7;
          const size_t idx = tb + ((size_t)kr)*512 + (size_t)((((cg ^ (kr & 7)) << 3)) | ci);
          Ykt[idx] = (_Float16)y;
        } else {
          const int bb = row >> 11, nn = row & 2047, kt = nn >> 5;
          const size_t tb = ((size_t)(bb*64 + kt)) << 14;
          const int kk = nn & 31;
          const size_t idx = tb + ((size_t)col)*32 + (size_t)(((((kk >> 3) ^ ((col >> 1) & 3)) << 3)) | (kk & 7));
          Yvt[idx] = (_Float16)y;
        }
      }
    }
  }
}

// ---------------- fused flash attention (round-7 structure, verbatim) ----------------
// K fp16 single, dbuf LDS. V fp16 single, dbuf LDS. Both staged at step top
// (full-step lead), ONE pre-drained vmcnt(0) per step. QK^T: 2-pass fp16
// (Q split hi/lo, exact; K rounded). PV: fp16. 3 barriers/step.
__global__ __launch_bounds__(512, 2) void attn_k(
    const _Float16* __restrict__ Qh, const _Float16* __restrict__ Ql,
    const _Float16* __restrict__ Kt,
    const _Float16* __restrict__ Vt,
    float* __restrict__ Out)
{
  __shared__ _Float16 K_lds[2][32][512];   // 64 KB dbuf (fp16 single, swizzled col)
  __shared__ _Float16 V_lds[2][512][32];   // 64 KB dbuf (fp16 single)
  __shared__ _Float16 P_s[64][40];         // 5 KB
  __shared__ float pm_s[64][2], ps_s[64][2];
  __shared__ float m_s[2][64], l_s[64], sc_s[64];

  const int bid = blockIdx.x;
  const int b  = bid & 7;
  const int qt = bid >> 3;
  const int tid = threadIdx.x;
  const int w = tid >> 6, lane = tid & 63;
  const int l15 = lane & 15, l4 = lane >> 4;
  const int rw = w & 3,  cw = w >> 2;   // S^T frag: q-rows rw*16.., k-cols cw*16..
  const int orw = w >> 2, ocw = w & 3;  // O: rows orw*32.., cols ocw*128..

  half8 qhf[16], qlf[16];
  {
    const size_t qoff = (size_t)(b*NQL + qt*64 + rw*16 + l15)*DD + l4*8;
    #pragma unroll
    for (int kc=0;kc<16;kc++){
      qhf[kc] = *reinterpret_cast<const half8*>(Qh + qoff + kc*32);
      qlf[kc] = *reinterpret_cast<const half8*>(Ql + qoff + kc*32);
    }
  }

  f32x4 o[2][8];
  #pragma unroll
  for (int i=0;i<2;i++)
    #pragma unroll
    for (int j=0;j<8;j++) o[i][j] = (f32x4){0.f,0.f,0.f,0.f};

  if (tid < 64){ m_s[0][tid] = -1e30f; l_s[tid] = 0.f; }

  const _Float16* gK = Kt + ((size_t)(b*64) << 14);
  const _Float16* gV = Vt + ((size_t)(b*64) << 14);
  const int goff  = w*512 + lane*8;   // fp16 elems
  const int lbase = w*512;            // wave-uniform dest base (fp16 elems)

  // prologue: stage K(0) + V(0) into buffers 0 (4+4 issues)
  {
    _Float16* lK = &K_lds[0][0][0];
    _Float16* lV = &V_lds[0][0][0];
    #pragma unroll
    for (int r=0;r<4;r++) stage16(gK + r*4096 + goff, lK + r*4096 + lbase);
    #pragma unroll
    for (int r=0;r<4;r++) stage16(gV + r*4096 + goff, lV + r*4096 + lbase);
  }

  const int krow = cw*16 + l15;
  const int kx = krow & 7;
  const int row_i = rw*16 + l15;     // this lane's q-row (local)

  #pragma unroll 1
  for (int kt=0; kt<64; ++kt){
    const int par = kt & 1;
    asm volatile("s_waitcnt vmcnt(0)" ::: "memory");   // K(kt), V(kt) resident (full-step lead)
    barrier_lgkm();                                    // bar A

    // stage K(kt+1)+V(kt+1) into the other buffers — full-step lead
    {
      const _Float16* gk1 = gK + ((size_t)((kt+1)&63) << 14);
      const _Float16* gv1 = gV + ((size_t)((kt+1)&63) << 14);
      _Float16* lK = &K_lds[par^1][0][0];
      _Float16* lV = &V_lds[par^1][0][0];
      #pragma unroll
      for (int r=0;r<4;r++) stage16(gk1 + r*4096 + goff, lK + r*4096 + lbase);
      #pragma unroll
      for (int r=0;r<4;r++) stage16(gv1 + r*4096 + goff, lV + r*4096 + lbase);
    }

    // ---- S^T = K Q^T (2-pass fp16: k single, q split) ----
    f32x4 shh = (f32x4){0.f,0.f,0.f,0.f};
    f32x4 shl = (f32x4){0.f,0.f,0.f,0.f};
    __builtin_amdgcn_s_setprio(1);
    #pragma unroll
    for (int kc=0;kc<16;kc++){
      const int cg = ((kc*4 + l4) ^ kx) << 3;
      const half8 kf = *reinterpret_cast<const half8*>(&K_lds[par][krow][cg]);
      shh = __builtin_amdgcn_mfma_f32_16x16x32_f16(kf, qhf[kc], shh, 0,0,0);
      shl = __builtin_amdgcn_mfma_f32_16x16x32_f16(kf, qlf[kc], shl, 0,0,0);
    }
    __builtin_amdgcn_s_setprio(0);
    const f32x4 sv = shh + shl;   // sv[r] = S[row_i][cw*16 + l4*4 + r]

    // ---- per-wave softmax partials ----
    float mw = fmaxf(fmaxf(sv[0],sv[1]), fmaxf(sv[2],sv[3]));
    mw = fmaxf(mw, __shfl_xor(mw, 16));
    mw = fmaxf(mw, __shfl_xor(mw, 32));
    float p0 = __expf(sv[0]-mw), p1 = __expf(sv[1]-mw);
    float p2 = __expf(sv[2]-mw), p3 = __expf(sv[3]-mw);
    float ssum = p0+p1+p2+p3;
    ssum += __shfl_xor(ssum, 16);
    ssum += __shfl_xor(ssum, 32);
    if (l4 == 0){ pm_s[row_i][cw] = mw; ps_s[row_i][cw] = ssum; }
    barrier_lgkm();                                    // bar B — partials ready

    // ---- combine partials, finalize P (fp16), write ----
    {
      const float m0 = pm_s[row_i][0], m1 = pm_s[row_i][1];
      const float m_old = m_s[par][row_i];
      const float m_new = fmaxf(fmaxf(m0, m1), m_old);
      const float c = __expf(mw - m_new);
      p0 *= c; p1 *= c; p2 *= c; p3 *= c;
      if (cw == 0 && l4 == 0){
        const float e_old = __expf(m_old - m_new);
        const float e1    = __expf(m1 - m_new);
        l_s[row_i] = l_s[row_i]*e_old + ps_s[row_i][0]*c + ps_s[row_i][1]*e1;
        m_s[par^1][row_i] = m_new;
        sc_s[row_i] = e_old;
      }
      const unsigned short h0 = __builtin_bit_cast(unsigned short, (_Float16)p0);
      const unsigned short h1 = __builtin_bit_cast(unsigned short, (_Float16)p1);
      const unsigned short h2 = __builtin_bit_cast(unsigned short, (_Float16)p2);
      const unsigned short h3 = __builtin_bit_cast(unsigned short, (_Float16)p3);
      uint2 hv;
      hv.x = (unsigned)h0 | ((unsigned)h1<<16);
      hv.y = (unsigned)h2 | ((unsigned)h3<<16);
      *reinterpret_cast<uint2*>(&P_s[row_i][cw*16 + l4*4]) = hv;
    }
    barrier_lgkm();                                    // bar C — P ready

    // ---- rescale O (skip when running max unchanged) ----
    {
      float scs[2][4];
      bool need = false;
      #pragma unroll
      for (int pr=0; pr<2; pr++)
        #pragma unroll
        for (int j=0;j<4;j++){
          const float s0 = sc_s[orw*32 + pr*16 + l4*4 + j];
          scs[pr][j] = s0;
          need = need || (s0 < 0.999999f);
        }
      if (__any(need)){
        #pragma unroll
        for (int pr=0;pr<2;pr++)
          #pragma unroll
          for (int c=0;c<8;c++)
            #pragma unroll
            for (int j=0;j<4;j++) o[pr][c][j] *= scs[pr][j];
      }
    }

    // ---- O += P V (fp16: 2 MFMA per cc) ----
    half8 pa[2];
    #pragma unroll
    for (int pr=0;pr<2;pr++){
      const int prow = orw*32 + pr*16 + l15;
      pa[pr] = *reinterpret_cast<const half8*>(&P_s[prow][l4*8]);
    }
    __builtin_amdgcn_s_setprio(1);
    #pragma unroll
    for (int cc=0; cc<8; ++cc){
      const int dcol = ocw*128 + cc*16 + l15;
      const int vb = (l4 ^ ((dcol>>1)&3)) << 3;
      const half8 vv = *reinterpret_cast<const half8*>(&V_lds[par][dcol][vb]);
      o[0][cc] = __builtin_amdgcn_mfma_f32_16x16x32_f16(pa[0], vv, o[0][cc], 0,0,0);
      o[1][cc] = __builtin_amdgcn_mfma_f32_16x16x32_f16(pa[1], vv, o[1][cc], 0,0,0);
    }
    __builtin_amdgcn_s_setprio(0);
    // no bar D: barA's lgkmcnt(0)+barrier orders P/K/V reuse; K,V parity-split
  }

  barrier_lgkm();   // l_s final visible

  #pragma unroll
  for (int pr=0;pr<2;pr++){
    #pragma unroll
    for (int j=0;j<4;j++){
      const int row = orw*32 + pr*16 + l4*4 + j;
      const float inv = 1.0f / l_s[row];
      const size_t obase = (size_t)(b*NQL + qt*64 + row)*DD;
      #pragma unroll
      for (int c=0;c<8;c++){
        const int col = ocw*128 + c*16 + l15;
        Out[obase + col] = o[pr][c][j]*inv;
      }
    }
  }
}

extern "C" void kernel_launch(void* const* d_in, const int* in_sizes, int n_in,
                              void* d_out, int out_size, void* d_ws, size_t ws_size,
                              hipStream_t stream) {
  const float* query = (const float*)d_in[0];
  const float* key   = (const float*)d_in[1];
  const float* value = (const float*)d_in[2];
  const float* Wq    = (const float*)d_in[3];
  const float* Wk    = (const float*)d_in[4];
  const float* Wv    = (const float*)d_in[5];
  float* out = (float*)d_out;

  const size_t SB = (size_t)NB*NQL*DD;   // 8,388,608 elems
  const size_t WB = (size_t)DD*DD;

  _Float16* p = (_Float16*)d_ws;
  _Float16 *w16q = p, *w16k = p + WB, *w16v = p + 2*WB;
  _Float16* q0 = p + 3*WB;
  _Float16 *qh16 = q0,          *ql16 = q0 + SB;
  _Float16 *Kt16 = q0 + 2*SB;                 // [8][64][32][512] fp16
  _Float16 *Vt16 = q0 + 3*SB;                 // [8][64][512][32] fp16

  dim3 sg(256, 3);
  split3_k<<<sg, 256, 0, stream>>>(Wq, Wk, Wv, w16q, w16k, w16v, (int)(WB/4));

  dim3 pg(128, 4, 3);
  proj2_k<<<pg, 256, 0, stream>>>(query, key, value,
                                  w16q, w16k, w16v,
                                  qh16, ql16, Kt16, Vt16);

  attn_k<<<256, 512, 0, stream>>>(qh16, ql16, Kt16, Vt16, out);
}

// Round 10
// 212.937 us; speedup vs baseline: 1.2412x; 1.1064x over previous
//
#include <hip/hip_runtime.h>

typedef __attribute__((ext_vector_type(8))) short short8;
typedef __attribute__((ext_vector_type(8))) _Float16 half8;
typedef __attribute__((ext_vector_type(4))) float f32x4;
typedef __attribute__((ext_vector_type(4))) unsigned short u16x4;
typedef __attribute__((ext_vector_type(4))) _Float16 half4;

#define NB 8
#define NQL 2048
#define NKL 2048
#define DD 512

static __device__ __forceinline__ void stage16(const void* g, void* l){
  __builtin_amdgcn_global_load_lds(
      (const __attribute__((address_space(1))) void*)g,
      (__attribute__((address_space(3))) void*)l, 16, 0, 0);
}

static __device__ __forceinline__ void barrier_lgkm(){
  asm volatile("s_waitcnt lgkmcnt(0)" ::: "memory");
  __builtin_amdgcn_s_barrier();
  asm volatile("" ::: "memory");
}

// ---------------- convert fp32 W -> fp16 single, all three in one launch ----------------
__global__ __launch_bounds__(256) void split3_k(
    const float* __restrict__ Wq, const float* __restrict__ Wk, const float* __restrict__ Wv,
    _Float16* __restrict__ w16q, _Float16* __restrict__ w16k, _Float16* __restrict__ w16v,
    int n4){
  const int z = blockIdx.y;
  const float* x = (z==0) ? Wq : (z==1) ? Wk : Wv;
  _Float16* o16 = (z==0) ? w16q : (z==1) ? w16k : w16v;
  int i = blockIdx.x*256 + threadIdx.x;
  if (i >= n4) return;
  f32x4 v = reinterpret_cast<const f32x4*>(x)[i];
  half4 h;
  #pragma unroll
  for (int j=0;j<4;j++) h[j] = (_Float16)v[j];
  reinterpret_cast<half4*>(o16)[i] = h;
}

// ---------------- fused projections: Y = X * W^T (128x128 tile, 2-pass fp16, dbuf) ----------------
__global__ __launch_bounds__(256, 2) void proj2_k(
    const float* __restrict__ Xq, const float* __restrict__ Xk, const float* __restrict__ Xv,
    const _Float16* __restrict__ W16q, const _Float16* __restrict__ W16k, const _Float16* __restrict__ W16v,
    _Float16* __restrict__ Yqh, _Float16* __restrict__ Yql,
    _Float16* __restrict__ Ykt,
    _Float16* __restrict__ Yvt)
{
  __shared__ _Float16 AB[2][3][128][32];   // 48 KB: planes 0=Ah 1=Al 2=W

  const int z = blockIdx.z;
  const float*    X  = (z==0) ? Xq   : (z==1) ? Xk   : Xv;
  const _Float16* Wf = (z==0) ? W16q : (z==1) ? W16k : W16v;

  const int mbase = blockIdx.x * 128;
  const int nbase = blockIdx.y * 128;
  const int tid = threadIdx.x;
  const int w = tid >> 6, lane = tid & 63;
  const int l15 = lane & 15, l4 = lane >> 4;
  const int wr = w >> 1, wc = w & 1;

  const int arow = tid >> 1, ahalf = tid & 1;
  const int brow_l = w*16 + (lane>>2);
  const int bkg    = (lane & 3) ^ ((lane >> 3) & 3);

  f32x4 acc[4][4];
  #pragma unroll
  for (int m=0;m<4;m++)
    #pragma unroll
    for (int n=0;n<4;n++) acc[m][n] = (f32x4){0.f,0.f,0.f,0.f};

  f32x4 xa[4];
  {
    const f32x4* xp = reinterpret_cast<const f32x4*>(X + (size_t)(mbase+arow)*DD + ahalf*16);
    #pragma unroll
    for (int q=0;q<4;q++) xa[q] = xp[q];
  }
  {
    _Float16* lB = &AB[0][2][0][0] + w*512;
    #pragma unroll
    for (int r=0;r<2;r++){
      const size_t gh = (size_t)(nbase + r*64 + brow_l)*DD + bkg*8;
      stage16(Wf + gh, lB + r*2048);
    }
  }
  {
    asm volatile("s_waitcnt vmcnt(2)" ::: "memory");
    half8 h0,h1,l0,l1;
    #pragma unroll
    for (int j=0;j<4;j++){
      float v0 = xa[0][j], v1 = xa[1][j];
      h0[j] = (_Float16)v0; h0[4+j] = (_Float16)v1;
      l0[j] = (_Float16)(v0 - (float)h0[j]); l0[4+j] = (_Float16)(v1 - (float)h0[4+j]);
      float v2 = xa[2][j], v3 = xa[3][j];
      h1[j] = (_Float16)v2; h1[4+j] = (_Float16)v3;
      l1[j] = (_Float16)(v2 - (float)h1[j]); l1[4+j] = (_Float16)(v3 - (float)h1[4+j]);
    }
    const int sw = (arow>>1)&3;
    const int cg0 = (ahalf*2) ^ sw, cg1 = (ahalf*2+1) ^ sw;
    *reinterpret_cast<half8*>(&AB[0][0][arow][cg0*8]) = h0;
    *reinterpret_cast<half8*>(&AB[0][0][arow][cg1*8]) = h1;
    *reinterpret_cast<half8*>(&AB[0][1][arow][cg0*8]) = l0;
    *reinterpret_cast<half8*>(&AB[0][1][arow][cg1*8]) = l1;
  }

  const int asw = (l15>>1)&3;

  #pragma unroll 1
  for (int s=0; s<16; ++s){
    const int cur = s&1, nxt = cur^1;
    asm volatile("s_waitcnt vmcnt(0)" ::: "memory");
    barrier_lgkm();

    if (s < 15){
      const f32x4* xp = reinterpret_cast<const f32x4*>(X + (size_t)(mbase+arow)*DD + (s+1)*32 + ahalf*16);
      #pragma unroll
      for (int q=0;q<4;q++) xa[q] = xp[q];
      _Float16* lB = &AB[nxt][2][0][0] + w*512;
      #pragma unroll
      for (int r=0;r<2;r++){
        const size_t gh = (size_t)(nbase + r*64 + brow_l)*DD + (s+1)*32 + bkg*8;
        stage16(Wf + gh, lB + r*2048);
      }
    }

    half8 ah[4], al[4], wf[4];
    #pragma unroll
    for (int m=0;m<4;m++){
      const int rA = wr*64 + m*16 + l15;
      const int cg = (l4 ^ asw)*8;
      ah[m] = *reinterpret_cast<const half8*>(&AB[cur][0][rA][cg]);
      al[m] = *reinterpret_cast<const half8*>(&AB[cur][1][rA][cg]);
    }
    #pragma unroll
    for (int n=0;n<4;n++){
      const int rB = wc*64 + n*16 + l15;
      const int cg = (l4 ^ asw)*8;
      wf[n] = *reinterpret_cast<const half8*>(&AB[cur][2][rB][cg]);
    }
    #pragma unroll
    for (int m=0;m<4;m++)
      #pragma unroll
      for (int n=0;n<4;n++) acc[m][n] = __builtin_amdgcn_mfma_f32_16x16x32_f16(ah[m], wf[n], acc[m][n], 0,0,0);
    #pragma unroll
    for (int m=0;m<4;m++)
      #pragma unroll
      for (int n=0;n<4;n++) acc[m][n] = __builtin_amdgcn_mfma_f32_16x16x32_f16(al[m], wf[n], acc[m][n], 0,0,0);

    if (s < 15){
      asm volatile("s_waitcnt vmcnt(2)" ::: "memory");
      half8 h0,h1,l0,l1;
      #pragma unroll
      for (int j=0;j<4;j++){
        float v0 = xa[0][j], v1 = xa[1][j];
        h0[j] = (_Float16)v0; h0[4+j] = (_Float16)v1;
        l0[j] = (_Float16)(v0 - (float)h0[j]); l0[4+j] = (_Float16)(v1 - (float)h0[4+j]);
        float v2 = xa[2][j], v3 = xa[3][j];
        h1[j] = (_Float16)v2; h1[4+j] = (_Float16)v3;
        l1[j] = (_Float16)(v2 - (float)h1[j]); l1[4+j] = (_Float16)(v3 - (float)h1[4+j]);
      }
      const int sw = (arow>>1)&3;
      const int cg0 = (ahalf*2) ^ sw, cg1 = (ahalf*2+1) ^ sw;
      *reinterpret_cast<half8*>(&AB[nxt][0][arow][cg0*8]) = h0;
      *reinterpret_cast<half8*>(&AB[nxt][0][arow][cg1*8]) = h1;
      *reinterpret_cast<half8*>(&AB[nxt][1][arow][cg0*8]) = l0;
      *reinterpret_cast<half8*>(&AB[nxt][1][arow][cg1*8]) = l1;
    }
  }

  #pragma unroll
  for (int m=0;m<4;m++){
    #pragma unroll
    for (int n=0;n<4;n++){
      #pragma unroll
      for (int j=0;j<4;j++){
        const int row = mbase + wr*64 + m*16 + l4*4 + j;
        const int col = nbase + wc*64 + n*16 + l15;
        const float y = acc[m][n][j];
        if (z == 0){
          const _Float16 h = (_Float16)y;
          const _Float16 l = (_Float16)(y - (float)h);
          const size_t idx = (size_t)row*DD + col;
          Yqh[idx] = h; Yql[idx] = l;
        } else if (z == 1){
          const int bb = row >> 11, nn = row & 2047, kt = nn >> 5;
          const size_t tb = ((size_t)(bb*64 + kt)) << 14;
          const int kr = nn & 31, cg = col >> 3, ci = col & 7;
          const size_t idx = tb + ((size_t)kr)*512 + (size_t)((((cg ^ (kr & 7)) << 3)) | ci);
          Ykt[idx] = (_Float16)y;
        } else {
          const int bb = row >> 11, nn = row & 2047, kt = nn >> 5;
          const size_t tb = ((size_t)(bb*64 + kt)) << 14;
          const int kk = nn & 31;
          const size_t idx = tb + ((size_t)col)*32 + (size_t)(((((kk >> 3) ^ ((col >> 1) & 3)) << 3)) | (kk & 7));
          Yvt[idx] = (_Float16)y;
        }
      }
    }
  }
}

// ---------------- fused flash attention: wave-specialized producer/consumer ----------------
// Waves 0-3 (QK): 16 q-rows each, full 32 k-cols; in-register softmax; publish P(t),sc(t).
// Waves 4-7 (PV): 16 q-rows x 512 d-cols of O; consume P(t-1),V(t-1). ONE barrier/step.
// K,V,P,sc parity double-buffered; stage K(t+1),V(t) at top of step t (full-step lead).
// Role-dependent register file: f32x4 r[32] = Q hi/lo frags (QK) or O accum (PV).
__global__ __launch_bounds__(512, 2) void attn_k(
    const _Float16* __restrict__ Qh, const _Float16* __restrict__ Ql,
    const _Float16* __restrict__ Kt,
    const _Float16* __restrict__ Vt,
    float* __restrict__ Out)
{
  __shared__ _Float16 K_lds[2][32][512];   // 64 KB dbuf
  __shared__ _Float16 V_lds[2][512][32];   // 64 KB dbuf
  __shared__ _Float16 P_s[2][64][40];      // 10 KB dbuf
  __shared__ float sc_s[2][64];
  __shared__ float l_s[64];

  const int bid = blockIdx.x;
  const int b  = bid & 7;
  const int qt = bid >> 3;
  const int tid = threadIdx.x;
  const int w = tid >> 6, lane = tid & 63;
  const int l15 = lane & 15, l4 = lane >> 4;
  const bool isQK = (w < 4);
  const int qw = w & 3;               // row-group for both roles

  const _Float16* gK = Kt + ((size_t)(b*64) << 14);
  const _Float16* gV = Vt + ((size_t)(b*64) << 14);
  const int goff  = w*512 + lane*8;
  const int lbase = w*512;

  // role-dependent register file (128 VGPRs, statically indexed)
  f32x4 r[32];
  float m_old = -1e30f, lacc = 0.f;
  if (isQK){
    const size_t qoff = (size_t)(b*NQL + qt*64 + qw*16 + l15)*DD + l4*8;
    #pragma unroll
    for (int kc=0;kc<16;kc++){
      r[kc]    = __builtin_bit_cast(f32x4, *reinterpret_cast<const half8*>(Qh + qoff + kc*32));
      r[16+kc] = __builtin_bit_cast(f32x4, *reinterpret_cast<const half8*>(Ql + qoff + kc*32));
    }
  } else {
    #pragma unroll
    for (int i=0;i<32;i++) r[i] = (f32x4){0.f,0.f,0.f,0.f};
  }

  // prologue: stage K(0) -> kb[0]
  {
    _Float16* lK = &K_lds[0][0][0];
    #pragma unroll
    for (int q=0;q<4;q++) stage16(gK + q*4096 + goff, lK + q*4096 + lbase);
  }

  const int kx = l15 & 7;
  const int row_i = qw*16 + l15;

  #pragma unroll 1
  for (int kt=0; kt<64; ++kt){
    const int par = kt & 1;
    asm volatile("s_waitcnt vmcnt(0)" ::: "memory");  // K(t), V(t-1) resident
    barrier_lgkm();                                   // + P(t-1)/sc(t-1) visible

    // stage K(t+1) -> kb[(t+1)&1], V(t) -> vb[t&1]  (drained at next barrier)
    if (kt < 63){
      const _Float16* g = gK + ((size_t)(kt+1) << 14);
      _Float16* lK = &K_lds[par^1][0][0];
      #pragma unroll
      for (int q=0;q<4;q++) stage16(g + q*4096 + goff, lK + q*4096 + lbase);
    }
    {
      const _Float16* g = gV + ((size_t)kt << 14);
      _Float16* lV = &V_lds[par][0][0];
      #pragma unroll
      for (int q=0;q<4;q++) stage16(g + q*4096 + goff, lV + q*4096 + lbase);
    }

    if (isQK){
      // ---- S(t): two col-frags, 2-pass fp16 ----
      f32x4 s0h = (f32x4){0.f,0.f,0.f,0.f}, s0l = (f32x4){0.f,0.f,0.f,0.f};
      f32x4 s1h = (f32x4){0.f,0.f,0.f,0.f}, s1l = (f32x4){0.f,0.f,0.f,0.f};
      __builtin_amdgcn_s_setprio(1);
      #pragma unroll
      for (int kc=0;kc<16;kc++){
        const int cg = ((kc*4 + l4) ^ kx) << 3;
        const half8 kf0 = *reinterpret_cast<const half8*>(&K_lds[par][l15][cg]);
        const half8 kf1 = *reinterpret_cast<const half8*>(&K_lds[par][16+l15][cg]);
        const half8 qh = __builtin_bit_cast(half8, r[kc]);
        const half8 ql = __builtin_bit_cast(half8, r[16+kc]);
        s0h = __builtin_amdgcn_mfma_f32_16x16x32_f16(kf0, qh, s0h, 0,0,0);
        s0l = __builtin_amdgcn_mfma_f32_16x16x32_f16(kf0, ql, s0l, 0,0,0);
        s1h = __builtin_amdgcn_mfma_f32_16x16x32_f16(kf1, qh, s1h, 0,0,0);
        s1l = __builtin_amdgcn_mfma_f32_16x16x32_f16(kf1, ql, s1l, 0,0,0);
      }
      __builtin_amdgcn_s_setprio(0);
      const f32x4 sv0 = s0h + s0l;   // cols l4*4+j
      const f32x4 sv1 = s1h + s1l;   // cols 16+l4*4+j

      // ---- wave-local softmax (full 32-col row per wave) ----
      float mw = fmaxf(fmaxf(fmaxf(sv0[0],sv0[1]), fmaxf(sv0[2],sv0[3])),
                       fmaxf(fmaxf(sv1[0],sv1[1]), fmaxf(sv1[2],sv1[3])));
      mw = fmaxf(mw, __shfl_xor(mw, 16));
      mw = fmaxf(mw, __shfl_xor(mw, 32));
      const float m_new = fmaxf(m_old, mw);
      const float p0 = __expf(sv0[0]-m_new), p1 = __expf(sv0[1]-m_new);
      const float p2 = __expf(sv0[2]-m_new), p3 = __expf(sv0[3]-m_new);
      const float p4 = __expf(sv1[0]-m_new), p5 = __expf(sv1[1]-m_new);
      const float p6 = __expf(sv1[2]-m_new), p7 = __expf(sv1[3]-m_new);
      float ssum = (p0+p1)+(p2+p3)+((p4+p5)+(p6+p7));
      ssum += __shfl_xor(ssum, 16);
      ssum += __shfl_xor(ssum, 32);
      const float e_old = __expf(m_old - m_new);
      lacc = lacc*e_old + ssum;
      m_old = m_new;
      if (l4 == 0) sc_s[par][row_i] = e_old;
      uint2 hv;
      hv.x = (unsigned)__builtin_bit_cast(unsigned short,(_Float16)p0) |
             ((unsigned)__builtin_bit_cast(unsigned short,(_Float16)p1)<<16);
      hv.y = (unsigned)__builtin_bit_cast(unsigned short,(_Float16)p2) |
             ((unsigned)__builtin_bit_cast(unsigned short,(_Float16)p3)<<16);
      *reinterpret_cast<uint2*>(&P_s[par][row_i][l4*4]) = hv;
      uint2 hw;
      hw.x = (unsigned)__builtin_bit_cast(unsigned short,(_Float16)p4) |
             ((unsigned)__builtin_bit_cast(unsigned short,(_Float16)p5)<<16);
      hw.y = (unsigned)__builtin_bit_cast(unsigned short,(_Float16)p6) |
             ((unsigned)__builtin_bit_cast(unsigned short,(_Float16)p7)<<16);
      *reinterpret_cast<uint2*>(&P_s[par][row_i][16 + l4*4]) = hw;
    } else if (kt > 0){
      const int pp = par^1;
      // ---- rescale O with sc(t-1) ----
      float scs[4];
      bool need = false;
      #pragma unroll
      for (int j=0;j<4;j++){
        scs[j] = sc_s[pp][qw*16 + l4*4 + j];
        need = need || (scs[j] < 0.999999f);
      }
      if (__any(need)){
        #pragma unroll
        for (int f=0;f<32;f++)
          #pragma unroll
          for (int j=0;j<4;j++) r[f][j] *= scs[j];
      }
      // ---- O += P(t-1) V(t-1) ----
      const half8 pa = *reinterpret_cast<const half8*>(&P_s[pp][row_i][l4*8]);
      __builtin_amdgcn_s_setprio(1);
      #pragma unroll
      for (int f=0;f<32;f++){
        const int dcol = f*16 + l15;
        const int vb = (l4 ^ ((dcol>>1)&3)) << 3;
        const half8 vv = *reinterpret_cast<const half8*>(&V_lds[pp][dcol][vb]);
        r[f] = __builtin_amdgcn_mfma_f32_16x16x32_f16(pa, vv, r[f], 0,0,0);
      }
      __builtin_amdgcn_s_setprio(0);
    }
  }

  // publish final l; drain V(63)
  if (isQK && l4 == 0) l_s[row_i] = lacc;
  asm volatile("s_waitcnt vmcnt(0)" ::: "memory");
  barrier_lgkm();

  if (!isQK){
    // rescale with sc(63) + PV(63) + normalize + store
    float scs[4];
    bool need = false;
    #pragma unroll
    for (int j=0;j<4;j++){
      scs[j] = sc_s[1][qw*16 + l4*4 + j];
      need = need || (scs[j] < 0.999999f);
    }
    if (__any(need)){
      #pragma unroll
      for (int f=0;f<32;f++)
        #pragma unroll
        for (int j=0;j<4;j++) r[f][j] *= scs[j];
    }
    const half8 pa = *reinterpret_cast<const half8*>(&P_s[1][row_i][l4*8]);
    #pragma unroll
    for (int f=0;f<32;f++){
      const int dcol = f*16 + l15;
      const int vb = (l4 ^ ((dcol>>1)&3)) << 3;
      const half8 vv = *reinterpret_cast<const half8*>(&V_lds[1][dcol][vb]);
      r[f] = __builtin_amdgcn_mfma_f32_16x16x32_f16(pa, vv, r[f], 0,0,0);
    }
    float inv[4];
    #pragma unroll
    for (int j=0;j<4;j++) inv[j] = 1.0f / l_s[qw*16 + l4*4 + j];
    #pragma unroll
    for (int j=0;j<4;j++){
      const int row = qw*16 + l4*4 + j;
      const size_t obase = (size_t)(b*NQL + qt*64 + row)*DD;
      #pragma unroll
      for (int f=0;f<32;f++){
        Out[obase + f*16 + l15] = r[f][j]*inv[j];
      }
    }
  }
}

extern "C" void kernel_launch(void* const* d_in, const int* in_sizes, int n_in,
                              void* d_out, int out_size, void* d_ws, size_t ws_size,
                              hipStream_t stream) {
  const float* query = (const float*)d_in[0];
  const float* key   = (const float*)d_in[1];
  const float* value = (const float*)d_in[2];
  const float* Wq    = (const float*)d_in[3];
  const float* Wk    = (const float*)d_in[4];
  const float* Wv    = (const float*)d_in[5];
  float* out = (float*)d_out;

  const size_t SB = (size_t)NB*NQL*DD;   // 8,388,608 elems
  const size_t WB = (size_t)DD*DD;

  _Float16* p = (_Float16*)d_ws;
  _Float16 *w16q = p, *w16k = p + WB, *w16v = p + 2*WB;
  _Float16* q0 = p + 3*WB;
  _Float16 *qh16 = q0,          *ql16 = q0 + SB;
  _Float16 *Kt16 = q0 + 2*SB;                 // [8][64][32][512] fp16
  _Float16 *Vt16 = q0 + 3*SB;                 // [8][64][512][32] fp16

  dim3 sg(256, 3);
  split3_k<<<sg, 256, 0, stream>>>(Wq, Wk, Wv, w16q, w16k, w16v, (int)(WB/4));

  dim3 pg(128, 4, 3);
  proj2_k<<<pg, 256, 0, stream>>>(query, key, value,
                                  w16q, w16k, w16v,
                                  qh16, ql16, Kt16, Vt16);

  attn_k<<<256, 512, 0, stream>>>(qh16, ql16, Kt16, Vt16, out);
}

// Round 11
// 208.388 us; speedup vs baseline: 1.2683x; 1.0218x over previous
//
#include <hip/hip_runtime.h>

typedef __attribute__((ext_vector_type(8))) short short8;
typedef __attribute__((ext_vector_type(8))) _Float16 half8;
typedef __attribute__((ext_vector_type(4))) float f32x4;
typedef __attribute__((ext_vector_type(4))) unsigned short u16x4;
typedef __attribute__((ext_vector_type(4))) _Float16 half4;

#define NB 8
#define NQL 2048
#define NKL 2048
#define DD 512

static __device__ __forceinline__ void stage16(const void* g, void* l){
  __builtin_amdgcn_global_load_lds(
      (const __attribute__((address_space(1))) void*)g,
      (__attribute__((address_space(3))) void*)l, 16, 0, 0);
}

static __device__ __forceinline__ void barrier_lgkm(){
  asm volatile("s_waitcnt lgkmcnt(0)" ::: "memory");
  __builtin_amdgcn_s_barrier();
  asm volatile("" ::: "memory");
}

// 4-lane-group reduce over lanes {i, i+16, i+32, i+48} via gfx950 permlane swaps (pure VALU)
static __device__ __forceinline__ float red4_max(float x){
  float a = x, b = x;
  asm volatile("v_permlane16_swap_b32 %0, %1" : "+v"(a), "+v"(b));
  x = fmaxf(a, b);
  a = x; b = x;
  asm volatile("v_permlane32_swap_b32 %0, %1" : "+v"(a), "+v"(b));
  return fmaxf(a, b);
}
static __device__ __forceinline__ float red4_sum(float x){
  float a = x, b = x;
  asm volatile("v_permlane16_swap_b32 %0, %1" : "+v"(a), "+v"(b));
  x = a + b;
  a = x; b = x;
  asm volatile("v_permlane32_swap_b32 %0, %1" : "+v"(a), "+v"(b));
  return a + b;
}

// ---------------- convert fp32 W -> fp16 single, all three in one launch ----------------
__global__ __launch_bounds__(256) void split3_k(
    const float* __restrict__ Wq, const float* __restrict__ Wk, const float* __restrict__ Wv,
    _Float16* __restrict__ w16q, _Float16* __restrict__ w16k, _Float16* __restrict__ w16v,
    int n4){
  const int z = blockIdx.y;
  const float* x = (z==0) ? Wq : (z==1) ? Wk : Wv;
  _Float16* o16 = (z==0) ? w16q : (z==1) ? w16k : w16v;
  int i = blockIdx.x*256 + threadIdx.x;
  if (i >= n4) return;
  f32x4 v = reinterpret_cast<const f32x4*>(x)[i];
  half4 h;
  #pragma unroll
  for (int j=0;j<4;j++) h[j] = (_Float16)v[j];
  reinterpret_cast<half4*>(o16)[i] = h;
}

// ---------------- fused projections: Y = X * W^T (128x128 tile, 2-pass fp16, dbuf) ----------------
__global__ __launch_bounds__(256, 2) void proj2_k(
    const float* __restrict__ Xq, const float* __restrict__ Xk, const float* __restrict__ Xv,
    const _Float16* __restrict__ W16q, const _Float16* __restrict__ W16k, const _Float16* __restrict__ W16v,
    _Float16* __restrict__ Yqh, _Float16* __restrict__ Yql,
    _Float16* __restrict__ Ykt,
    _Float16* __restrict__ Yvt)
{
  __shared__ _Float16 AB[2][3][128][32];   // 48 KB: planes 0=Ah 1=Al 2=W

  const int z = blockIdx.z;
  const float*    X  = (z==0) ? Xq   : (z==1) ? Xk   : Xv;
  const _Float16* Wf = (z==0) ? W16q : (z==1) ? W16k : W16v;

  const int mbase = blockIdx.x * 128;
  const int nbase = blockIdx.y * 128;
  const int tid = threadIdx.x;
  const int w = tid >> 6, lane = tid & 63;
  const int l15 = lane & 15, l4 = lane >> 4;
  const int wr = w >> 1, wc = w & 1;

  const int arow = tid >> 1, ahalf = tid & 1;
  const int brow_l = w*16 + (lane>>2);
  const int bkg    = (lane & 3) ^ ((lane >> 3) & 3);

  f32x4 acc[4][4];
  #pragma unroll
  for (int m=0;m<4;m++)
    #pragma unroll
    for (int n=0;n<4;n++) acc[m][n] = (f32x4){0.f,0.f,0.f,0.f};

  f32x4 xa[4];
  {
    const f32x4* xp = reinterpret_cast<const f32x4*>(X + (size_t)(mbase+arow)*DD + ahalf*16);
    #pragma unroll
    for (int q=0;q<4;q++) xa[q] = xp[q];
  }
  {
    _Float16* lB = &AB[0][2][0][0] + w*512;
    #pragma unroll
    for (int r=0;r<2;r++){
      const size_t gh = (size_t)(nbase + r*64 + brow_l)*DD + bkg*8;
      stage16(Wf + gh, lB + r*2048);
    }
  }
  {
    asm volatile("s_waitcnt vmcnt(2)" ::: "memory");
    half8 h0,h1,l0,l1;
    #pragma unroll
    for (int j=0;j<4;j++){
      float v0 = xa[0][j], v1 = xa[1][j];
      h0[j] = (_Float16)v0; h0[4+j] = (_Float16)v1;
      l0[j] = (_Float16)(v0 - (float)h0[j]); l0[4+j] = (_Float16)(v1 - (float)h0[4+j]);
      float v2 = xa[2][j], v3 = xa[3][j];
      h1[j] = (_Float16)v2; h1[4+j] = (_Float16)v3;
      l1[j] = (_Float16)(v2 - (float)h1[j]); l1[4+j] = (_Float16)(v3 - (float)h1[4+j]);
    }
    const int sw = (arow>>1)&3;
    const int cg0 = (ahalf*2) ^ sw, cg1 = (ahalf*2+1) ^ sw;
    *reinterpret_cast<half8*>(&AB[0][0][arow][cg0*8]) = h0;
    *reinterpret_cast<half8*>(&AB[0][0][arow][cg1*8]) = h1;
    *reinterpret_cast<half8*>(&AB[0][1][arow][cg0*8]) = l0;
    *reinterpret_cast<half8*>(&AB[0][1][arow][cg1*8]) = l1;
  }

  const int asw = (l15>>1)&3;

  #pragma unroll 1
  for (int s=0; s<16; ++s){
    const int cur = s&1, nxt = cur^1;
    asm volatile("s_waitcnt vmcnt(0)" ::: "memory");
    barrier_lgkm();

    if (s < 15){
      const f32x4* xp = reinterpret_cast<const f32x4*>(X + (size_t)(mbase+arow)*DD + (s+1)*32 + ahalf*16);
      #pragma unroll
      for (int q=0;q<4;q++) xa[q] = xp[q];
      _Float16* lB = &AB[nxt][2][0][0] + w*512;
      #pragma unroll
      for (int r=0;r<2;r++){
        const size_t gh = (size_t)(nbase + r*64 + brow_l)*DD + (s+1)*32 + bkg*8;
        stage16(Wf + gh, lB + r*2048);
      }
    }

    half8 ah[4], al[4], wf[4];
    #pragma unroll
    for (int m=0;m<4;m++){
      const int rA = wr*64 + m*16 + l15;
      const int cg = (l4 ^ asw)*8;
      ah[m] = *reinterpret_cast<const half8*>(&AB[cur][0][rA][cg]);
      al[m] = *reinterpret_cast<const half8*>(&AB[cur][1][rA][cg]);
    }
    #pragma unroll
    for (int n=0;n<4;n++){
      const int rB = wc*64 + n*16 + l15;
      const int cg = (l4 ^ asw)*8;
      wf[n] = *reinterpret_cast<const half8*>(&AB[cur][2][rB][cg]);
    }
    #pragma unroll
    for (int m=0;m<4;m++)
      #pragma unroll
      for (int n=0;n<4;n++) acc[m][n] = __builtin_amdgcn_mfma_f32_16x16x32_f16(ah[m], wf[n], acc[m][n], 0,0,0);
    #pragma unroll
    for (int m=0;m<4;m++)
      #pragma unroll
      for (int n=0;n<4;n++) acc[m][n] = __builtin_amdgcn_mfma_f32_16x16x32_f16(al[m], wf[n], acc[m][n], 0,0,0);

    if (s < 15){
      asm volatile("s_waitcnt vmcnt(2)" ::: "memory");
      half8 h0,h1,l0,l1;
      #pragma unroll
      for (int j=0;j<4;j++){
        float v0 = xa[0][j], v1 = xa[1][j];
        h0[j] = (_Float16)v0; h0[4+j] = (_Float16)v1;
        l0[j] = (_Float16)(v0 - (float)h0[j]); l0[4+j] = (_Float16)(v1 - (float)h0[4+j]);
        float v2 = xa[2][j], v3 = xa[3][j];
        h1[j] = (_Float16)v2; h1[4+j] = (_Float16)v3;
        l1[j] = (_Float16)(v2 - (float)h1[j]); l1[4+j] = (_Float16)(v3 - (float)h1[4+j]);
      }
      const int sw = (arow>>1)&3;
      const int cg0 = (ahalf*2) ^ sw, cg1 = (ahalf*2+1) ^ sw;
      *reinterpret_cast<half8*>(&AB[nxt][0][arow][cg0*8]) = h0;
      *reinterpret_cast<half8*>(&AB[nxt][0][arow][cg1*8]) = h1;
      *reinterpret_cast<half8*>(&AB[nxt][1][arow][cg0*8]) = l0;
      *reinterpret_cast<half8*>(&AB[nxt][1][arow][cg1*8]) = l1;
    }
  }

  #pragma unroll
  for (int m=0;m<4;m++){
    #pragma unroll
    for (int n=0;n<4;n++){
      #pragma unroll
      for (int j=0;j<4;j++){
        const int row = mbase + wr*64 + m*16 + l4*4 + j;
        const int col = nbase + wc*64 + n*16 + l15;
        const float y = acc[m][n][j];
        if (z == 0){
          const _Float16 h = (_Float16)y;
          const _Float16 l = (_Float16)(y - (float)h);
          const size_t idx = (size_t)row*DD + col;
          Yqh[idx] = h; Yql[idx] = l;
        } else if (z == 1){
          const int bb = row >> 11, nn = row & 2047, kt = nn >> 5;
          const size_t tb = ((size_t)(bb*64 + kt)) << 14;
          const int kr = nn & 31, cg = col >> 3, ci = col & 7;
          const size_t idx = tb + ((size_t)kr)*512 + (size_t)((((cg ^ (kr & 7)) << 3)) | ci);
          Ykt[idx] = (_Float16)y;
        } else {
          const int bb = row >> 11, nn = row & 2047, kt = nn >> 5;
          const size_t tb = ((size_t)(bb*64 + kt)) << 14;
          const int kk = nn & 31;
          const size_t idx = tb + ((size_t)col)*32 + (size_t)(((((kk >> 3) ^ ((col >> 1) & 3)) << 3)) | (kk & 7));
          Yvt[idx] = (_Float16)y;
        }
      }
    }
  }
}

// ---------------- fused flash attention: wave-specialized + defer-max + permlane softmax ----------------
// Waves 0-3 (QK): 16 q-rows each, all 32 k-cols; in-register softmax with speculative
// exp(s - m_old) overlapped with the permlane max-reduce; row max update deferred unless
// it jumps by >8 (P bounded by e^8, fp16-safe). Waves 4-7 (PV): consume P(t-1),V(t-1).
// ONE barrier/step; K,V,P,sc parity double-buffered; full-step staging lead.
__global__ __launch_bounds__(512, 2) void attn_k(
    const _Float16* __restrict__ Qh, const _Float16* __restrict__ Ql,
    const _Float16* __restrict__ Kt,
    const _Float16* __restrict__ Vt,
    float* __restrict__ Out)
{
  __shared__ _Float16 K_lds[2][32][512];   // 64 KB dbuf
  __shared__ _Float16 V_lds[2][512][32];   // 64 KB dbuf
  __shared__ _Float16 P_s[2][64][40];      // 10 KB dbuf
  __shared__ float sc_s[2][64];
  __shared__ float l_s[64];

  const int bid = blockIdx.x;
  const int b  = bid & 7;
  const int qt = bid >> 3;
  const int tid = threadIdx.x;
  const int w = tid >> 6, lane = tid & 63;
  const int l15 = lane & 15, l4 = lane >> 4;
  const bool isQK = (w < 4);
  const int qw = w & 3;

  const _Float16* gK = Kt + ((size_t)(b*64) << 14);
  const _Float16* gV = Vt + ((size_t)(b*64) << 14);
  const int goff  = w*512 + lane*8;
  const int lbase = w*512;

  // role-dependent register file (128 VGPRs, statically indexed)
  f32x4 r[32];
  float m_old = -1e30f, lacc = 0.f;
  if (isQK){
    const size_t qoff = (size_t)(b*NQL + qt*64 + qw*16 + l15)*DD + l4*8;
    #pragma unroll
    for (int kc=0;kc<16;kc++){
      r[kc]    = __builtin_bit_cast(f32x4, *reinterpret_cast<const half8*>(Qh + qoff + kc*32));
      r[16+kc] = __builtin_bit_cast(f32x4, *reinterpret_cast<const half8*>(Ql + qoff + kc*32));
    }
  } else {
    #pragma unroll
    for (int i=0;i<32;i++) r[i] = (f32x4){0.f,0.f,0.f,0.f};
  }

  // prologue: stage K(0) -> kb[0]
  {
    _Float16* lK = &K_lds[0][0][0];
    #pragma unroll
    for (int q=0;q<4;q++) stage16(gK + q*4096 + goff, lK + q*4096 + lbase);
  }

  const int kx = l15 & 7;
  const int row_i = qw*16 + l15;

  #pragma unroll 1
  for (int kt=0; kt<64; ++kt){
    const int par = kt & 1;
    asm volatile("s_waitcnt vmcnt(0)" ::: "memory");  // K(t), V(t-1) resident
    barrier_lgkm();                                   // + P(t-1)/sc(t-1) visible

    // stage K(t+1) -> kb[(t+1)&1], V(t) -> vb[t&1]
    if (kt < 63){
      const _Float16* g = gK + ((size_t)(kt+1) << 14);
      _Float16* lK = &K_lds[par^1][0][0];
      #pragma unroll
      for (int q=0;q<4;q++) stage16(g + q*4096 + goff, lK + q*4096 + lbase);
    }
    {
      const _Float16* g = gV + ((size_t)kt << 14);
      _Float16* lV = &V_lds[par][0][0];
      #pragma unroll
      for (int q=0;q<4;q++) stage16(g + q*4096 + goff, lV + q*4096 + lbase);
    }

    if (isQK){
      // ---- S(t): two col-frags, 2-pass fp16 ----
      f32x4 s0h = (f32x4){0.f,0.f,0.f,0.f}, s0l = (f32x4){0.f,0.f,0.f,0.f};
      f32x4 s1h = (f32x4){0.f,0.f,0.f,0.f}, s1l = (f32x4){0.f,0.f,0.f,0.f};
      __builtin_amdgcn_s_setprio(1);
      #pragma unroll
      for (int kc=0;kc<16;kc++){
        const int cg = ((kc*4 + l4) ^ kx) << 3;
        const half8 kf0 = *reinterpret_cast<const half8*>(&K_lds[par][l15][cg]);
        const half8 kf1 = *reinterpret_cast<const half8*>(&K_lds[par][16+l15][cg]);
        const half8 qh = __builtin_bit_cast(half8, r[kc]);
        const half8 ql = __builtin_bit_cast(half8, r[16+kc]);
        s0h = __builtin_amdgcn_mfma_f32_16x16x32_f16(kf0, qh, s0h, 0,0,0);
        s0l = __builtin_amdgcn_mfma_f32_16x16x32_f16(kf0, ql, s0l, 0,0,0);
        s1h = __builtin_amdgcn_mfma_f32_16x16x32_f16(kf1, qh, s1h, 0,0,0);
        s1l = __builtin_amdgcn_mfma_f32_16x16x32_f16(kf1, ql, s1l, 0,0,0);
      }
      __builtin_amdgcn_s_setprio(0);
      const f32x4 sv0 = s0h + s0l;
      const f32x4 sv1 = s1h + s1l;

      // ---- softmax: speculative exp(m_old) overlapped with permlane max-reduce ----
      float mw = fmaxf(fmaxf(fmaxf(sv0[0],sv0[1]), fmaxf(sv0[2],sv0[3])),
                       fmaxf(fmaxf(sv1[0],sv1[1]), fmaxf(sv1[2],sv1[3])));
      float p0 = __expf(sv0[0]-m_old), p1 = __expf(sv0[1]-m_old);
      float p2 = __expf(sv0[2]-m_old), p3 = __expf(sv0[3]-m_old);
      float p4 = __expf(sv1[0]-m_old), p5 = __expf(sv1[1]-m_old);
      float p6 = __expf(sv1[2]-m_old), p7 = __expf(sv1[3]-m_old);
      mw = red4_max(mw);                       // row-uniform across the 4 lanes
      float e_old = 1.0f;
      if (mw > m_old + 8.0f){                  // rare after warmup
        e_old = __expf(m_old - mw);
        p0 = __expf(sv0[0]-mw); p1 = __expf(sv0[1]-mw);
        p2 = __expf(sv0[2]-mw); p3 = __expf(sv0[3]-mw);
        p4 = __expf(sv1[0]-mw); p5 = __expf(sv1[1]-mw);
        p6 = __expf(sv1[2]-mw); p7 = __expf(sv1[3]-mw);
        m_old = mw;
      }
      if (l4 == 0) sc_s[par][row_i] = e_old;
      uint2 hv;
      hv.x = (unsigned)__builtin_bit_cast(unsigned short,(_Float16)p0) |
             ((unsigned)__builtin_bit_cast(unsigned short,(_Float16)p1)<<16);
      hv.y = (unsigned)__builtin_bit_cast(unsigned short,(_Float16)p2) |
             ((unsigned)__builtin_bit_cast(unsigned short,(_Float16)p3)<<16);
      *reinterpret_cast<uint2*>(&P_s[par][row_i][l4*4]) = hv;
      uint2 hw;
      hw.x = (unsigned)__builtin_bit_cast(unsigned short,(_Float16)p4) |
             ((unsigned)__builtin_bit_cast(unsigned short,(_Float16)p5)<<16);
      hw.y = (unsigned)__builtin_bit_cast(unsigned short,(_Float16)p6) |
             ((unsigned)__builtin_bit_cast(unsigned short,(_Float16)p7)<<16);
      *reinterpret_cast<uint2*>(&P_s[par][row_i][16 + l4*4]) = hw;
      // sum-reduce is pure VALU (permlane) — can slide past the barrier
      float ssum = (p0+p1)+(p2+p3)+((p4+p5)+(p6+p7));
      ssum = red4_sum(ssum);
      lacc = lacc*e_old + ssum;
    } else if (kt > 0){
      const int pp = par^1;
      // ---- rescale O with sc(t-1) (sc==1 after defer-max warmup -> skipped) ----
      float scs[4];
      bool need = false;
      #pragma unroll
      for (int j=0;j<4;j++){
        scs[j] = sc_s[pp][qw*16 + l4*4 + j];
        need = need || (scs[j] < 0.999999f);
      }
      if (__any(need)){
        #pragma unroll
        for (int f=0;f<32;f++)
          #pragma unroll
          for (int j=0;j<4;j++) r[f][j] *= scs[j];
      }
      // ---- O += P(t-1) V(t-1) ----
      const half8 pa = *reinterpret_cast<const half8*>(&P_s[pp][row_i][l4*8]);
      __builtin_amdgcn_s_setprio(1);
      #pragma unroll
      for (int f=0;f<32;f++){
        const int dcol = f*16 + l15;
        const int vb = (l4 ^ ((dcol>>1)&3)) << 3;
        const half8 vv = *reinterpret_cast<const half8*>(&V_lds[pp][dcol][vb]);
        r[f] = __builtin_amdgcn_mfma_f32_16x16x32_f16(pa, vv, r[f], 0,0,0);
      }
      __builtin_amdgcn_s_setprio(0);
    }
  }

  // publish final l; drain V(63)
  if (isQK && l4 == 0) l_s[row_i] = lacc;
  asm volatile("s_waitcnt vmcnt(0)" ::: "memory");
  barrier_lgkm();

  if (!isQK){
    float scs[4];
    bool need = false;
    #pragma unroll
    for (int j=0;j<4;j++){
      scs[j] = sc_s[1][qw*16 + l4*4 + j];
      need = need || (scs[j] < 0.999999f);
    }
    if (__any(need)){
      #pragma unroll
      for (int f=0;f<32;f++)
        #pragma unroll
        for (int j=0;j<4;j++) r[f][j] *= scs[j];
    }
    const half8 pa = *reinterpret_cast<const half8*>(&P_s[1][row_i][l4*8]);
    #pragma unroll
    for (int f=0;f<32;f++){
      const int dcol = f*16 + l15;
      const int vb = (l4 ^ ((dcol>>1)&3)) << 3;
      const half8 vv = *reinterpret_cast<const half8*>(&V_lds[1][dcol][vb]);
      r[f] = __builtin_amdgcn_mfma_f32_16x16x32_f16(pa, vv, r[f], 0,0,0);
    }
    float inv[4];
    #pragma unroll
    for (int j=0;j<4;j++) inv[j] = 1.0f / l_s[qw*16 + l4*4 + j];
    #pragma unroll
    for (int j=0;j<4;j++){
      const int row = qw*16 + l4*4 + j;
      const size_t obase = (size_t)(b*NQL + qt*64 + row)*DD;
      #pragma unroll
      for (int f=0;f<32;f++){
        Out[obase + f*16 + l15] = r[f][j]*inv[j];
      }
    }
  }
}

extern "C" void kernel_launch(void* const* d_in, const int* in_sizes, int n_in,
                              void* d_out, int out_size, void* d_ws, size_t ws_size,
                              hipStream_t stream) {
  const float* query = (const float*)d_in[0];
  const float* key   = (const float*)d_in[1];
  const float* value = (const float*)d_in[2];
  const float* Wq    = (const float*)d_in[3];
  const float* Wk    = (const float*)d_in[4];
  const float* Wv    = (const float*)d_in[5];
  float* out = (float*)d_out;

  const size_t SB = (size_t)NB*NQL*DD;   // 8,388,608 elems
  const size_t WB = (size_t)DD*DD;

  _Float16* p = (_Float16*)d_ws;
  _Float16 *w16q = p, *w16k = p + WB, *w16v = p + 2*WB;
  _Float16* q0 = p + 3*WB;
  _Float16 *qh16 = q0,          *ql16 = q0 + SB;
  _Float16 *Kt16 = q0 + 2*SB;                 // [8][64][32][512] fp16
  _Float16 *Vt16 = q0 + 3*SB;                 // [8][64][512][32] fp16

  dim3 sg(256, 3);
  split3_k<<<sg, 256, 0, stream>>>(Wq, Wk, Wv, w16q, w16k, w16v, (int)(WB/4));

  dim3 pg(128, 4, 3);
  proj2_k<<<pg, 256, 0, stream>>>(query, key, value,
                                  w16q, w16k, w16v,
                                  qh16, ql16, Kt16, Vt16);

  attn_k<<<256, 512, 0, stream>>>(qh16, ql16, Kt16, Vt16, out);
}